// Round 17
// baseline (695.454 us; speedup 1.0000x reference)
//
#include <hip/hip_runtime.h>
#include <hip/hip_bf16.h>
#include <math.h>

typedef __hip_bfloat16 bf16;
typedef unsigned short us;
typedef __attribute__((ext_vector_type(8))) short short8v;
typedef __attribute__((ext_vector_type(4))) float f32x4;
#define DEV static __device__ __forceinline__
DEV float b2f(bf16 x){ return __bfloat162float(x); }
DEV bf16  f2b(float x){ return __float2bfloat16(x); }
DEV us    f2u(float x){ bf16 h=f2b(x); return *(us*)&h; }
DEV float u2f(us u){ return __uint_as_float(((unsigned)u)<<16); }
DEV float blo(unsigned int w){ return __uint_as_float(w<<16); }
DEV float bhi(unsigned int w){ return __uint_as_float(w&0xffff0000u); }
DEV float ldin(const void* p, long i, int f){
  return f ? ((const float*)p)[i] : b2f(((const bf16*)p)[i]);
}

// problem dims
#define PP 25088            // t*h*w = 8*56*56

// ws layout (float units)
#define POOLo  3211264L
#define XW1o   3286528L
#define WXo    3361792L     // Wx f32 208000; re-aliased by Wrr2 after k_Wfrag
#define WXTo   3569792L     // Wf MFMA A-frags: 256000 bf16
#define WIXo   3825792L
#define ATTo   3832064L     // 2*13*25088 f32
#define KERNo  4484352L     // kern bf16 [b][kk][p] (uses half the old f32 region)
#define XW3o   6942976L     // xw3 bf16
#define STATo  8147200L
#define FLAGo  8149248L
#define WFo    8149264L
#define WATTFo 8267280L     // W_att f32; dead after k_Wx -> bias2 aliases head
#define WINVFo 9222784L
#define BF16o  9251600L
#define WRR2o  WXo
// bf16 sub-offsets (bf16 element units)
#define bX1T   3211264L     // x1t [b][p][64] 3211264
#define bXATT  8028160L     // xattT [b][p][256] 12845056
#define bY1    20873216L    // y1T [b][p][256] 12845056 (xwt aliases head until k_p1)
#define bINV   33718272L    // invT [b][p][256] 12845056
#define bWP1B  46563328L    // Wp1b bf16 raw [co][ci] 65536
#define bWP2B  46628864L    // Wp2b bf16 raw [o][ci] 16384
#define bW2S   46645248L    // W2sb bf16 [o][ci] 16384
#define bXWT   bY1          // xwt [b][d][hw][64]; dead before k_p1 writes y1T
// wf sub-offsets
#define oWCT   0
#define oBCT   4096
#define oWWSI  4160
#define oBWSI  8256
#define oWRR   8320
#define oBINV  35968
#define oWP1   36032
#define oWP2   101568       // [ci][co] 256x64
#define oBP2   117952

// ---- input dtype probe ----
__global__ void k_detect(const us* raw, int* flag){
  int t = threadIdx.x;
  us u = raw[2*t];
  int e = (u>>7)&0xFF;
  int hit = (e >= 137);
  unsigned long long m = __ballot(hit);
  if(t==0) flag[0] = (__popcll(m) >= 8) ? 1 : 0;
}

// ---- merged weight prep: Wattf, Winvf, wf, Wp1b, Wp2b ----
__global__ void k_prep(const void* Watt,const void* Winv,const void* Wct,const void* bct,
                       const void* Wwsi,const void* bwsi,const void* Wrr,const void* binv,
                       const void* Wp1,const void* Wp2,const void* bp2,
                       float* Wattf,float* Winvf,float* wf,us* Wp1b,us* Wp2b,const int* flag){
  int i = blockIdx.x*256 + threadIdx.x;
  int f = flag[0];
  if(i<955500) Wattf[i]=ldin(Watt,i,f);
  if(i<28812)  Winvf[i]=ldin(Winv,i,f);
  if(i<65536)  Wp1b[i]=f2u(ldin(Wp1,i,f));
  else if(i<81920) Wp2b[i-65536]=f2u(ldin(Wp2,i-65536,f));
  if (i < 4096){ int co=i>>6, ci=i&63; wf[oWCT + ci*64+co] = ldin(Wct,i,f); }
  else if (i < 4160){ wf[i] = ldin(bct,i-4096,f); }
  else if (i < 8256){ wf[i] = ldin(Wwsi,i-4160,f); }
  else if (i < 8320){ wf[i] = ldin(bwsi,i-8256,f); }
  else if (i < 35968){ int l=i-8320; int co=l/1728, r=l%1728, ci=r/27, tp=r%27;
                       wf[oWRR + (ci*27+tp)*16+co] = ldin(Wrr,l,f); }
  else if (i < 36017){ wf[oBINV + (i-35968)] = ldin(binv,i-35968,f); }
  else if (i < 36032){ }
  else if (i < 118016){
    int l=i-36032;
    if(l<65536){ int co=l>>8, ci=l&255; wf[oWP1 + ci*256+co] = ldin(Wp1,l,f); }
    else if(l<81920){ int l2=l-65536; int o=l2>>8, ci=l2&255; wf[oWP2 + ci*64+o] = ldin(Wp2,l2,f); }
    else if(l<81984){ wf[oBP2 + (l-81920)] = ldin(bp2,l-81920,f); }
  }
}

// ---- xwt = channel-last x_WSI [b][d][hw][64] straight from raw input ----
__global__ void k_wsit(const void* xwsi_r, const int* flag, us* xwt){
  __shared__ us tl[64*68];
  int tid=threadIdx.x; int p0=blockIdx.x*64; int d=blockIdx.y; int b=blockIdx.z;
  int f=flag[0];
  #pragma unroll
  for(int k=0;k<16;k++){
    int idx=k*256+tid; int px=idx&63, c=idx>>6;
    float v = ldin(xwsi_r, ((long)(b*64+c)*12+d)*3136 + p0+px, f);
    tl[px*68+c] = f2u(v);
  }
  __syncthreads();
  #pragma unroll
  for(int k=0;k<16;k++){
    int idx=k*256+tid; int px=idx>>6, ch=idx&63;
    xwt[((size_t)(b*12+d)*3136 + p0+px)*64 + ch] = tl[px*68+ch];
  }
}

// ---- fused adaptive-pool + xw1 (one block per (m,b), 64 threads) ----
__global__ __launch_bounds__(64) void k_poolxw1(const us* xwt, const float* wf, float* xw1){
  __shared__ float pl[64];
  int c=threadIdx.x; int m=blockIdx.x; int b=blockIdx.y;
  int d=m/49, r=m%49, ii=r/7, jj=r%7;
  const us* src = xwt + ((size_t)(b*12+d)*3136 + (ii*8)*56 + jj*8)*64 + c;
  float s=0;
  #pragma unroll
  for(int u=0;u<8;u++)
    #pragma unroll
    for(int v=0;v<8;v++) s += u2f(src[(size_t)(u*56+v)*64]);
  pl[c] = s*(1.f/64.f);
  __syncthreads();
  const float* w = wf + oWWSI + c*64;
  float o = wf[oBWSI + c];
  for(int ci=0;ci<64;ci++) o += w[ci]*pl[ci];
  xw1[(b*588+m)*64+c] = o;
}

// ---- Wx[b,o,tap,c] = sum_m W_att[o,m,tap] * xw1[b,c,m] ----
__global__ void k_Wx(const float* Wattf, const float* xw1, float* Wx){
  int i = blockIdx.x*256+threadIdx.x; if(i>=208000) return;
  int c=i&63; int r=i>>6; int tap=r%125; int o=(r/125)%13; int b=r/1625;
  const float* wa = Wattf + (size_t)o*588*125 + tap;
  const float* xp = xw1 + b*588*64 + c;
  float s=0;
  for(int m=0;m<588;m++) s += wa[(size_t)m*125] * xp[m*64];
  Wx[i]=s;
}

// ---- Wf: MFMA A-fragments for k_att ----
__global__ void k_Wfrag(const float* Wx, us* Wf){
  int i = blockIdx.x*256+threadIdx.x; if(i>=256000) return;
  int j=i&7; int m=(i>>3)&15; int kg=(i>>7)&3; int ch=(i>>9)&1;
  int r=i>>10; int tap=r%125; int b=r/125;
  int c = ch*32 + kg*8 + j;
  float v = (m<13) ? Wx[((size_t)(b*13+m)*125+tap)*64 + c] : 0.f;
  Wf[i] = f2u(v);
}

// ---- Wrr2: MFMA A-fragments for k_rr ----
__global__ void k_rrfrag(const float* wf, us* Wrr2){
  int i = blockIdx.x*256+threadIdx.x; if(i>=27648) return;
  int j=i&7; int l=(i>>3)&63; int kg=(i>>9)&1; int td=i>>10;
  int m=l&15, g=l>>4;
  int c = kg*32 + g*8 + j;
  Wrr2[i] = f2u(wf[oWRR + (c*27+td)*16 + m]);
}

// ---- Winvx: m-split 8-way, atomic accumulate (Wix pre-zeroed) ----
__global__ void k_Winvx(const float* Winvf, const float* xw1, float* Wix){
  int i = blockIdx.x*256+threadIdx.x; if(i>=6272) return;
  int ms = blockIdx.y;
  int kk=i%49; int c=(i/49)&63; int b=i/3136;
  int m0=ms*74; int m1=m0+74; if(m1>588) m1=588;
  const float* xp = xw1 + b*588*64 + c;
  float s=0;
  for(int m=m0;m<m1;m++) s += Winvf[kk*588+m] * xp[m*64];
  atomicAdd(&Wix[i], s);
}

// ---- x1t = bf16 channel-last (W_ct * x_CT + b), reads raw input ----
__global__ void k_x1(const void* xct_r, const int* flag, const float* wf, us* x1t){
  int p = blockIdx.x*256+threadIdx.x;
  int co0 = blockIdx.y*16; int b = blockIdx.z;
  float acc[16];
  #pragma unroll
  for(int o=0;o<16;o++) acc[o]=wf[oBCT+co0+o];
  int f=flag[0];
  if(f){
    const float* xp = (const float*)xct_r + (size_t)b*64*PP + p;
    for(int ci=0;ci<64;ci++){
      float xv = xp[(size_t)ci*PP];
      const float* w = wf + oWCT + ci*64 + co0;
      #pragma unroll
      for(int o=0;o<16;o++) acc[o] += w[o]*xv;
    }
  } else {
    const bf16* xp = (const bf16*)xct_r + (size_t)b*64*PP + p;
    for(int ci=0;ci<64;ci++){
      float xv = b2f(xp[(size_t)ci*PP]);
      const float* w = wf + oWCT + ci*64 + co0;
      #pragma unroll
      for(int o=0;o<16;o++) acc[o] += w[o]*xv;
    }
  }
  unsigned int pk[8];
  #pragma unroll
  for(int o2=0;o2<8;o2++)
    pk[o2] = (unsigned)f2u(acc[2*o2]) | ((unsigned)f2u(acc[2*o2+1])<<16);
  us* xo = x1t + ((size_t)(b*PP)+p)*64 + co0;
  *(uint4*)xo     = make_uint4(pk[0],pk[1],pk[2],pk[3]);
  *(uint4*)(xo+8) = make_uint4(pk[4],pk[5],pk[6],pk[7]);
}

// ---- Att = sigmoid(conv5x5x5) via MFMA implicit GEMM ----
__global__ __launch_bounds__(256) void k_att(const us* x1t, const us* Wf, float* att){
  __shared__ short xt[10368];
  int tid=threadIdx.x;
  int tile=blockIdx.x, t=blockIdx.y, b=blockIdx.z;
  int y0=(tile/7)*8, x0=(tile%7)*8;
  int w=tid>>6, l=tid&63;
  int pc=l&7, pr=(l>>3)&1, g=l>>4;
  f32x4 acc0={0,0,0,0}, acc1={0,0,0,0};
  int bbase = ((2*w+pr)*12 + pc)*72 + g*8;
  const us* Wb = Wf + (size_t)b*128000 + l*8;
  for(int dt=0;dt<5;dt++){
    int ti=t+dt-2;
    if(ti<0||ti>=8) continue;
    __syncthreads();
    for(int e=tid;e<1152;e+=256){
      int px=e>>3, q=e&7;
      int row=px/12, col=px-row*12;
      int gy=y0+row-2, gx=x0+col-2;
      uint4 v={0,0,0,0};
      if((unsigned)gy<56u && (unsigned)gx<56u)
        v = *(const uint4*)(x1t + ((size_t)(b*PP) + ti*3136 + gy*56 + gx)*64 + q*8);
      *(uint4*)&xt[px*72 + q*8] = v;
    }
    __syncthreads();
    const us* Wd = Wb + dt*25600;
    #pragma unroll
    for(int dy=0;dy<5;dy++){
      #pragma unroll
      for(int dx=0;dx<5;dx++){
        int off = bbase + dy*864 + dx*72;
        short8v a0 = *(const short8v*)(Wd + (dy*5+dx)*1024);
        short8v b0 = *(const short8v*)&xt[off];
        acc0 = __builtin_amdgcn_mfma_f32_16x16x32_bf16(a0,b0,acc0,0,0,0);
        short8v a1 = *(const short8v*)(Wd + (dy*5+dx)*1024 + 512);
        short8v b1 = *(const short8v*)&xt[off+32];
        acc1 = __builtin_amdgcn_mfma_f32_16x16x32_bf16(a1,b1,acc1,0,0,0);
      }
    }
  }
  int px=l&15; int epc=px&7, epr=px>>3;
  size_t pbase=(size_t)t*3136+(size_t)(y0+2*w+epr)*56+x0+epc;
  #pragma unroll
  for(int r=0;r<4;r++){
    int o=g*4+r;
    if(o<13){
      float s=acc0[r]+acc1[r];
      att[((size_t)b*13+o)*PP+pbase]=1.f/(1.f+__expf(-s));
    }
  }
}

// ---- kern49 = Winvx * x1 + b_inv (bf16 output) ----
__global__ void k_kern(const us* x1t, const float* Wix, const float* wf, bf16* kern){
  int p = blockIdx.x*256+threadIdx.x; int b=blockIdx.y;
  float acc[49];
  #pragma unroll
  for(int kk=0;kk<49;kk++) acc[kk]=wf[oBINV+kk];
  const us* xp = x1t + ((size_t)b*PP + p)*64;
  #pragma unroll
  for(int c8=0;c8<8;c8++){
    uint4 v = *(const uint4*)(xp + c8*8);
    const us* vp=(const us*)&v;
    #pragma unroll
    for(int j=0;j<8;j++){
      float xv = u2f(vp[j]);
      const float* w = Wix + (b*64+c8*8+j)*49;
      #pragma unroll
      for(int kk=0;kk<49;kk++) acc[kk]+=w[kk]*xv;
    }
  }
  bf16* out = kern + (size_t)b*49*PP + p;
  #pragma unroll
  for(int kk=0;kk<49;kk++) out[(size_t)kk*PP]=f2b(acc[kk]);
}

// ---- xw3 = conv3x3x3 via MFMA implicit GEMM ----
__global__ __launch_bounds__(256) void k_rr(const us* xwt, const us* Wrr2, bf16* xw3){
  __shared__ short xt[7200];
  int tid=threadIdx.x;
  int tile=blockIdx.x, d=blockIdx.y, b=blockIdx.z;
  int y0=(tile/7)*8, x0=(tile%7)*8;
  int w=tid>>6, l=tid&63;
  int pc=l&7, pr=(l>>3)&1, g=l>>4;
  f32x4 acc0={0,0,0,0}, acc1={0,0,0,0};
  int bbase = ((2*w+pr)*10 + pc)*72 + g*8;
  const us* Wl = Wrr2 + l*8;
  for(int dz=0;dz<3;dz++){
    int di=d+dz-1;
    if(di<0||di>=12) continue;
    __syncthreads();
    for(int e=tid;e<800;e+=256){
      int px=e>>3, q=e&7;
      int row=px/10, col=px-row*10;
      int gy=y0+row-1, gx=x0+col-1;
      uint4 v={0,0,0,0};
      if((unsigned)gy<56u && (unsigned)gx<56u)
        v = *(const uint4*)(xwt + ((size_t)(b*12+di)*3136 + gy*56 + gx)*64 + q*8);
      *(uint4*)&xt[px*72 + q*8] = v;
    }
    __syncthreads();
    const us* Wd = Wl + dz*9216;
    #pragma unroll
    for(int tap=0;tap<9;tap++){
      int dy=tap/3, dx=tap-dy*3;
      int off = bbase + (dy*10+dx)*72;
      short8v a0 = *(const short8v*)(Wd + tap*1024);
      short8v b0 = *(const short8v*)&xt[off];
      acc0 = __builtin_amdgcn_mfma_f32_16x16x32_bf16(a0,b0,acc0,0,0,0);
      short8v a1 = *(const short8v*)(Wd + tap*1024 + 512);
      short8v b1 = *(const short8v*)&xt[off+32];
      acc1 = __builtin_amdgcn_mfma_f32_16x16x32_bf16(a1,b1,acc1,0,0,0);
    }
  }
  int px=l&15; int epc=px&7, epr=px>>3;
  size_t pp=(size_t)(y0+2*w+epr)*56 + x0+epc;
  #pragma unroll
  for(int r=0;r<4;r++){
    int o=g*4+r;
    xw3[((size_t)(b*16+o)*12+d)*3136 + pp] = f2b(acc0[r]+acc1[r]);
  }
}

// ---- xattT = channel-last x_Att [b][p][256] (reads raw xct) ----
__global__ void k_xatt(const void* xct_r, const int* flag, const bf16* xw3,
                       const float* att, us* xattT){
  __shared__ us tl[64*258];
  int tid=threadIdx.x; int p0=blockIdx.x*64; int b=blockIdx.y;
  int f=flag[0];
  for(int k=0;k<64;k++){
    int idx=k*256+tid; int ch=idx>>6, pp=idx&63;
    int p=p0+pp;
    float v;
    if(ch<64){
      long ix = (long)(b*64+ch)*PP+p;
      float xv;
      if(f) xv = ((const float*)xct_r)[ix]; else xv = b2f(((const bf16*)xct_r)[ix]);
      v = xv * (1.f+att[(size_t)b*13*PP+p]);
    } else {
      int q=ch-64; int co=q/12, dd=q-co*12;
      int s=p%3136;
      v = b2f(xw3[((size_t)(b*16+co)*12+dd)*3136+s]) * (1.f+att[((size_t)b*13+1+q/16)*PP+p]);
    }
    tl[pp*258+ch]=f2u(v);
  }
  __syncthreads();
  for(int k=0;k<64;k++)
    xattT[((size_t)b*PP + p0+k)*256 + tid] = tl[k*258+tid];
}

// ---- y1T = x_Att @ W_p1^T ; LDS-staged weights; fused bn1 stats ----
__global__ __launch_bounds__(256) void k_p1(const us* xattT, const us* Wp1b, us* y1T,
                                            float* sum1, float* sq1){
  __shared__ us wt[16384];
  int tid=threadIdx.x; int w=tid>>6, l=tid&63;
  int pt=blockIdx.x, qtr=blockIdx.y, b=blockIdx.z;
  int co0 = qtr*64;
  #pragma unroll
  for(int it=0;it<8;it++){
    int f = it*256+tid;
    int n=f>>9, kc=(f>>6)&7, lane=f&63;
    int co = co0 + n*16 + (lane&15);
    int ci = (lane>>4)*8 + kc*32;
    uint4 v = *(const uint4*)(Wp1b + (size_t)co*256 + ci);
    *(uint4*)(wt + f*8) = v;
  }
  __syncthreads();
  int p0 = pt*64 + w*16;
  const us* xa = xattT + ((size_t)b*PP + p0 + (l&15))*256 + ((l>>4)*8);
  f32x4 acc[4];
  #pragma unroll
  for(int n=0;n<4;n++) acc[n]=(f32x4){0,0,0,0};
  for(int kc=0;kc<8;kc++){
    short8v a = *(const short8v*)(xa + kc*32);
    #pragma unroll
    for(int n=0;n<4;n++){
      short8v bf = *(const short8v*)(wt + ((n*8+kc)*64 + l)*8);
      acc[n] = __builtin_amdgcn_mfma_f32_16x16x32_bf16(a,bf,acc[n],0,0,0);
    }
  }
  int col=l&15, rowb=(l>>4)*4;
  us* yo = y1T + ((size_t)b*PP + p0)*256 + co0;
  #pragma unroll
  for(int n=0;n<4;n++){
    float sv=0, qv=0;
    #pragma unroll
    for(int r=0;r<4;r++){
      float x = acc[n][r];
      yo[(size_t)(rowb+r)*256 + n*16 + col] = f2u(x);
      sv += x; qv += x*x;
    }
    sv += __shfl_xor(sv,16,64); sv += __shfl_xor(sv,32,64);
    qv += __shfl_xor(qv,16,64); qv += __shfl_xor(qv,32,64);
    if((l>>4)==0){
      atomicAdd(&sum1[co0+n*16+col],sv);
      atomicAdd(&sq1[co0+n*16+col],qv);
    }
  }
}

__global__ void k_finstat(const float* sum, const float* sq, const void* g, const void* be,
                          const int* flag, float* sc, float* sh){
  int ch=threadIdx.x;
  int f=flag[0];
  float m = sum[ch]*(1.f/50176.f);
  float v = sq[ch]*(1.f/50176.f) - m*m;
  float s = ldin(g,ch,f) * rsqrtf(v+1e-5f);
  sc[ch]=s; sh[ch]=ldin(be,ch,f) - m*s;
}

// ---- involution, bn1+relu fused into staging; bf16 kern; fused bn2 stats ----
__global__ __launch_bounds__(256) void k_inv(const us* y1T, const float* sc1, const float* sh1,
                                             const bf16* kern, us* invT,
                                             float* sum2, float* sq2){
  __shared__ __align__(16) us xt[196*72];
  int tid=threadIdx.x;
  int bx=blockIdx.x, by=blockIdx.y, bz=blockIdx.z;
  int t=bz&7, b=bz>>3;
  int y0=(bx/7)*8, x0=(bx%7)*8, c0=by*64;
  int w=tid>>6, l=tid&63;
  int ty=l>>3, tx=l&7;
  int segb = c0 + (tid&7)*8;
  float scr[8], shr[8];
  #pragma unroll
  for(int j=0;j<8;j++){ scr[j]=sc1[segb+j]; shr[j]=sh1[segb+j]; }
  for(int e=tid;e<1568;e+=256){
    int row=e>>3, seg=e&7;                       // seg == tid&7
    int yy=row/14, xx=row%14;
    int gy=y0+yy-3, gx=x0+xx-3;
    uint4 o4={0,0,0,0};
    if(gy>=0&&gy<56&&gx>=0&&gx<56){
      uint4 v = *(const uint4*)&y1T[((size_t)b*PP + t*3136 + gy*56+gx)*256 + c0 + seg*8];
      const us* vp=(const us*)&v;
      us r[8];
      #pragma unroll
      for(int j=0;j<8;j++){
        float x = u2f(vp[j]);
        x = x*scr[j]+shr[j]; x = x>0.f?x:0.f;
        r[j]=f2u(x);
      }
      o4 = *(const uint4*)r;
    }
    *(uint4*)&xt[row*72+seg*8]=o4;
  }
  float kr[49];
  size_t pxs=(size_t)t*3136 + (y0+ty)*56 + x0+tx;
  #pragma unroll
  for(int kk=0;kk<49;kk++) kr[kk]=b2f(kern[((size_t)b*49+kk)*PP+pxs]);
  __syncthreads();
  #pragma unroll
  for(int s=0;s<2;s++){
    int sub=2*w+s;
    float acc[8];
    #pragma unroll
    for(int e=0;e<8;e++) acc[e]=0;
    for(int i=0;i<7;i++){
      #pragma unroll
      for(int j=0;j<7;j++){
        uint4 u = *(const uint4*)&xt[((ty+i)*14+tx+j)*72 + sub*8];
        float kv = kr[i*7+j];
        acc[0]+=kv*blo(u.x); acc[1]+=kv*bhi(u.x);
        acc[2]+=kv*blo(u.y); acc[3]+=kv*bhi(u.y);
        acc[4]+=kv*blo(u.z); acc[5]+=kv*bhi(u.z);
        acc[6]+=kv*blo(u.w); acc[7]+=kv*bhi(u.w);
      }
    }
    unsigned pk[4];
    #pragma unroll
    for(int e=0;e<4;e++)
      pk[e] = (unsigned)f2u(acc[2*e]) | ((unsigned)f2u(acc[2*e+1])<<16);
    *(uint4*)&invT[((size_t)b*PP+pxs)*256 + c0 + sub*8] = make_uint4(pk[0],pk[1],pk[2],pk[3]);
    // fused bn2 stats: reduce over the wave's 64 pixels
    #pragma unroll
    for(int e=0;e<8;e++){
      float sv=acc[e], qv=acc[e]*acc[e];
      #pragma unroll
      for(int m=32;m>0;m>>=1){ sv+=__shfl_xor(sv,m,64); qv+=__shfl_xor(qv,m,64); }
      if(l==0){
        atomicAdd(&sum2[c0+sub*8+e],sv);
        atomicAdd(&sq2[c0+sub*8+e],qv);
      }
    }
  }
}

// ---- W2s = W_p2*diag(sc2) bf16; bias2 = b_p2 + W_p2@sh2 ----
__global__ void k_w2s(const float* wf, const float* sc2, const float* sh2,
                      us* W2sb, float* bias2){
  __shared__ float red[256];
  int o=blockIdx.x, ci=threadIdx.x;
  float wv = wf[oWP2 + ci*64 + o];
  W2sb[o*256+ci] = f2u(wv * sc2[ci]);
  red[ci] = wv * sh2[ci];
  __syncthreads();
  for(int st=128;st>0;st>>=1){ if(ci<st) red[ci]+=red[ci+st]; __syncthreads(); }
  if(ci==0) bias2[o] = wf[oBP2+o] + red[0];
}

// ---- out = W2s@invT + W_p2@xattT + bias2 ; both weight panels LDS-staged ----
__global__ __launch_bounds__(256) void k_final(const us* invT, const us* xattT,
                                               const us* W2sb, const us* Wp2b,
                                               const float* bias2, float* out){
  __shared__ us wt[32768];
  int tid=threadIdx.x; int w=tid>>6, l=tid&63;
  int pt=blockIdx.x, b=blockIdx.y;
  #pragma unroll
  for(int it=0;it<16;it++){
    int f = it*256+tid;
    int which = f>>11;
    int g = f&2047;
    int n=g>>9, kc=(g>>6)&7, lane=g&63;
    int co = n*16 + (lane&15);
    int ci = (lane>>4)*8 + kc*32;
    const us* src = which ? Wp2b : W2sb;
    uint4 v = *(const uint4*)(src + (size_t)co*256 + ci);
    *(uint4*)(wt + f*8) = v;
  }
  __syncthreads();
  int p0 = pt*64 + w*16;
  size_t abase = ((size_t)b*PP + p0 + (l&15))*256 + ((l>>4)*8);
  f32x4 acc[4];
  #pragma unroll
  for(int n=0;n<4;n++) acc[n]=(f32x4){0,0,0,0};
  for(int kc=0;kc<8;kc++){
    short8v ai = *(const short8v*)(invT + abase + kc*32);
    short8v ax = *(const short8v*)(xattT + abase + kc*32);
    #pragma unroll
    for(int n=0;n<4;n++){
      short8v b1 = *(const short8v*)(wt + ((n*8+kc)*64 + l)*8);
      acc[n] = __builtin_amdgcn_mfma_f32_16x16x32_bf16(ai,b1,acc[n],0,0,0);
      short8v b2 = *(const short8v*)(wt + 16384 + ((n*8+kc)*64 + l)*8);
      acc[n] = __builtin_amdgcn_mfma_f32_16x16x32_bf16(ax,b2,acc[n],0,0,0);
    }
  }
  int col=l&15, rowb=(l>>4)*4;
  #pragma unroll
  for(int n=0;n<4;n++){
    float bb = bias2[n*16+col];
    #pragma unroll
    for(int r=0;r<4;r++)
      out[((size_t)b*64 + n*16+col)*PP + p0 + rowb + r] = acc[n][r] + bb;
  }
}

extern "C" void kernel_launch(void* const* d_in, const int* in_sizes, int n_in,
                              void* d_out, int out_size, void* d_ws, size_t ws_size,
                              hipStream_t stream){
  const void* xct_r =d_in[0];
  const void* xwsi_r=d_in[1];
  const void* Wct =d_in[2];
  const void* bct =d_in[3];
  const void* Wwsi=d_in[4];
  const void* bwsi=d_in[5];
  const void* Watt=d_in[6];
  const void* Winv=d_in[7];
  const void* binv=d_in[8];
  const void* Wrr =d_in[9];
  const void* g1  =d_in[10];
  const void* be1 =d_in[11];
  const void* g2  =d_in[12];
  const void* be2 =d_in[13];
  const void* Wp1 =d_in[14];
  const void* Wp2 =d_in[16];
  const void* bp2 =d_in[17];
  float* ws=(float*)d_ws;
  float* xw1=ws+XW1o;
  float* Wx=ws+WXo; float* Wix=ws+WIXo;
  float* att=ws+ATTo;
  bf16* kern=(bf16*)(ws+KERNo);
  us* Wf=(us*)(ws+WXTo);
  us* Wrr2=(us*)(ws+WRR2o);
  bf16* xw3=(bf16*)(ws+XW3o);
  float* stat=ws+STATo; float* wf=ws+WFo;
  float* Wattf=ws+WATTFo; float* Winvf=ws+WINVFo;
  float* bias2=ws+WATTFo;     // aliases Wattf (dead after k_Wx)
  int* flag=(int*)(ws+FLAGo);
  bf16* bfb=(bf16*)(ws+BF16o);
  us* x1t=(us*)(bfb+bX1T);
  us* xattT=(us*)(bfb+bXATT); us* y1T=(us*)(bfb+bY1); us* invT=(us*)(bfb+bINV);
  us* Wp1b=(us*)(bfb+bWP1B); us* Wp2b=(us*)(bfb+bWP2B); us* W2sb=(us*)(bfb+bW2S);
  us* xwt=(us*)(bfb+bXWT);
  float* sum1=stat; float* sq1=stat+256; float* sum2=stat+512; float* sq2=stat+768;
  float* sc1=stat+1024; float* sh1=stat+1280; float* sc2=stat+1536; float* sh2=stat+1792;

  hipMemsetAsync(stat,0,4096,stream);
  hipMemsetAsync(Wix,0,6272*4,stream);
  k_detect<<<1,64,0,stream>>>((const us*)xct_r,flag);
  k_prep  <<<3733,256,0,stream>>>(Watt,Winv,Wct,bct,Wwsi,bwsi,Wrr,binv,Wp1,Wp2,bp2,
                                  Wattf,Winvf,wf,Wp1b,Wp2b,flag);
  k_wsit  <<<dim3(49,12,2),256,0,stream>>>(xwsi_r,flag,xwt); // xwt aliases y1T head
  k_poolxw1<<<dim3(588,2),64,0,stream>>>(xwt,wf,xw1);
  k_Wx    <<<813,256,0,stream>>>(Wattf,xw1,Wx);
  k_Wfrag <<<1000,256,0,stream>>>(Wx,Wf);
  k_rrfrag<<<108,256,0,stream>>>(wf,Wrr2);                   // overwrites Wx head (dead)
  k_Winvx <<<dim3(25,8),256,0,stream>>>(Winvf,xw1,Wix);
  k_x1    <<<dim3(98,4,2),256,0,stream>>>(xct_r,flag,wf,x1t);
  k_att   <<<dim3(49,8,2),256,0,stream>>>(x1t,Wf,att);
  k_kern  <<<dim3(98,2),256,0,stream>>>(x1t,Wix,wf,kern);
  k_rr    <<<dim3(49,12,2),256,0,stream>>>(xwt,Wrr2,xw3);
  k_xatt  <<<dim3(392,2),256,0,stream>>>(xct_r,flag,xw3,att,xattT);
  k_p1    <<<dim3(392,4,2),256,0,stream>>>(xattT,Wp1b,y1T,sum1,sq1); // fused stats
  k_finstat<<<1,256,0,stream>>>(sum1,sq1,g1,be1,flag,sc1,sh1);
  k_inv   <<<dim3(49,4,16),256,0,stream>>>(y1T,sc1,sh1,kern,invT,sum2,sq2); // fused stats
  k_finstat<<<1,256,0,stream>>>(sum2,sq2,g2,be2,flag,sc2,sh2);
  k_w2s   <<<64,256,0,stream>>>(wf,sc2,sh2,W2sb,bias2);
  k_final <<<dim3(392,2),256,0,stream>>>(invT,xattT,W2sb,Wp2b,bias2,(float*)d_out);
}

// Round 18
// 366.916 us; speedup vs baseline: 1.8954x; 1.8954x over previous
//
#include <hip/hip_runtime.h>
#include <hip/hip_bf16.h>
#include <math.h>

typedef __hip_bfloat16 bf16;
typedef unsigned short us;
typedef __attribute__((ext_vector_type(8))) short short8v;
typedef __attribute__((ext_vector_type(4))) float f32x4;
#define DEV static __device__ __forceinline__
DEV float b2f(bf16 x){ return __bfloat162float(x); }
DEV bf16  f2b(float x){ return __float2bfloat16(x); }
DEV us    f2u(float x){ bf16 h=f2b(x); return *(us*)&h; }
DEV float u2f(us u){ return __uint_as_float(((unsigned)u)<<16); }
DEV float blo(unsigned int w){ return __uint_as_float(w<<16); }
DEV float bhi(unsigned int w){ return __uint_as_float(w&0xffff0000u); }
DEV float ldin(const void* p, long i, int f){
  return f ? ((const float*)p)[i] : b2f(((const bf16*)p)[i]);
}

// problem dims
#define PP 25088            // t*h*w = 8*56*56

// ws layout (float units)
#define POOLo  3211264L
#define XW1o   3286528L
#define WXo    3361792L     // Wx f32 208000; re-aliased by Wrr2 after k_Wfrag
#define WXTo   3569792L     // Wf MFMA A-frags: 256000 bf16
#define WIXo   3825792L
#define ATTo   3832064L     // 2*13*25088 f32
#define KERNo  4484352L     // kern bf16 [b][kk][p]
#define XW3o   6942976L     // xw3 bf16
#define STATo  8147200L
#define FLAGo  8149248L
#define WFo    8149264L
#define WATTFo 8267280L     // W_att f32; dead after k_Wx -> bias2 aliases head
#define WINVFo 9222784L
#define BF16o  9251600L
#define WRR2o  WXo
// bf16 sub-offsets (bf16 element units)
#define bX1T   3211264L     // x1t [b][p][64] 3211264
#define bXATT  8028160L     // xattT [b][p][256] 12845056
#define bY1    20873216L    // y1T [b][p][256] 12845056 (xwt aliases head until k_p1)
#define bINV   33718272L    // invT [b][p][256] 12845056
#define bWP1B  46563328L    // Wp1b bf16 raw [co][ci] 65536
#define bWP2B  46628864L    // Wp2b bf16 raw [o][ci] 16384
#define bW2S   46645248L    // W2sb bf16 [o][ci] 16384
#define bXWT   bY1          // xwt [b][d][hw][64]; dead before k_p1 writes y1T
// wf sub-offsets
#define oWCT   0
#define oBCT   4096
#define oWWSI  4160
#define oBWSI  8256
#define oWRR   8320
#define oBINV  35968
#define oWP1   36032
#define oWP2   101568       // [ci][co] 256x64
#define oBP2   117952

// ---- input dtype probe ----
__global__ void k_detect(const us* raw, int* flag){
  int t = threadIdx.x;
  us u = raw[2*t];
  int e = (u>>7)&0xFF;
  int hit = (e >= 137);
  unsigned long long m = __ballot(hit);
  if(t==0) flag[0] = (__popcll(m) >= 8) ? 1 : 0;
}

// ---- merged weight prep: Wattf, Winvf, wf, Wp1b, Wp2b ----
__global__ void k_prep(const void* Watt,const void* Winv,const void* Wct,const void* bct,
                       const void* Wwsi,const void* bwsi,const void* Wrr,const void* binv,
                       const void* Wp1,const void* Wp2,const void* bp2,
                       float* Wattf,float* Winvf,float* wf,us* Wp1b,us* Wp2b,const int* flag){
  int i = blockIdx.x*256 + threadIdx.x;
  int f = flag[0];
  if(i<955500) Wattf[i]=ldin(Watt,i,f);
  if(i<28812)  Winvf[i]=ldin(Winv,i,f);
  if(i<65536)  Wp1b[i]=f2u(ldin(Wp1,i,f));
  else if(i<81920) Wp2b[i-65536]=f2u(ldin(Wp2,i-65536,f));
  if (i < 4096){ int co=i>>6, ci=i&63; wf[oWCT + ci*64+co] = ldin(Wct,i,f); }
  else if (i < 4160){ wf[i] = ldin(bct,i-4096,f); }
  else if (i < 8256){ wf[i] = ldin(Wwsi,i-4160,f); }
  else if (i < 8320){ wf[i] = ldin(bwsi,i-8256,f); }
  else if (i < 35968){ int l=i-8320; int co=l/1728, r=l%1728, ci=r/27, tp=r%27;
                       wf[oWRR + (ci*27+tp)*16+co] = ldin(Wrr,l,f); }
  else if (i < 36017){ wf[oBINV + (i-35968)] = ldin(binv,i-35968,f); }
  else if (i < 36032){ }
  else if (i < 118016){
    int l=i-36032;
    if(l<65536){ int co=l>>8, ci=l&255; wf[oWP1 + ci*256+co] = ldin(Wp1,l,f); }
    else if(l<81920){ int l2=l-65536; int o=l2>>8, ci=l2&255; wf[oWP2 + ci*64+o] = ldin(Wp2,l2,f); }
    else if(l<81984){ wf[oBP2 + (l-81920)] = ldin(bp2,l-81920,f); }
  }
}

// ---- xwt = channel-last x_WSI [b][d][hw][64] straight from raw input ----
__global__ void k_wsit(const void* xwsi_r, const int* flag, us* xwt){
  __shared__ us tl[64*68];
  int tid=threadIdx.x; int p0=blockIdx.x*64; int d=blockIdx.y; int b=blockIdx.z;
  int f=flag[0];
  #pragma unroll
  for(int k=0;k<16;k++){
    int idx=k*256+tid; int px=idx&63, c=idx>>6;
    float v = ldin(xwsi_r, ((long)(b*64+c)*12+d)*3136 + p0+px, f);
    tl[px*68+c] = f2u(v);
  }
  __syncthreads();
  #pragma unroll
  for(int k=0;k<16;k++){
    int idx=k*256+tid; int px=idx>>6, ch=idx&63;
    xwt[((size_t)(b*12+d)*3136 + p0+px)*64 + ch] = tl[px*68+ch];
  }
}

// ---- fused adaptive-pool + xw1 (one block per (m,b), 64 threads) ----
__global__ __launch_bounds__(64) void k_poolxw1(const us* xwt, const float* wf, float* xw1){
  __shared__ float pl[64];
  int c=threadIdx.x; int m=blockIdx.x; int b=blockIdx.y;
  int d=m/49, r=m%49, ii=r/7, jj=r%7;
  const us* src = xwt + ((size_t)(b*12+d)*3136 + (ii*8)*56 + jj*8)*64 + c;
  float s=0;
  #pragma unroll
  for(int u=0;u<8;u++)
    #pragma unroll
    for(int v=0;v<8;v++) s += u2f(src[(size_t)(u*56+v)*64]);
  pl[c] = s*(1.f/64.f);
  __syncthreads();
  const float* w = wf + oWWSI + c*64;
  float o = wf[oBWSI + c];
  for(int ci=0;ci<64;ci++) o += w[ci]*pl[ci];
  xw1[(b*588+m)*64+c] = o;
}

// ---- Wx[b,o,tap,c] = sum_m W_att[o,m,tap] * xw1[b,c,m] ----
__global__ void k_Wx(const float* Wattf, const float* xw1, float* Wx){
  int i = blockIdx.x*256+threadIdx.x; if(i>=208000) return;
  int c=i&63; int r=i>>6; int tap=r%125; int o=(r/125)%13; int b=r/1625;
  const float* wa = Wattf + (size_t)o*588*125 + tap;
  const float* xp = xw1 + b*588*64 + c;
  float s=0;
  for(int m=0;m<588;m++) s += wa[(size_t)m*125] * xp[m*64];
  Wx[i]=s;
}

// ---- Wf: MFMA A-fragments for k_att ----
__global__ void k_Wfrag(const float* Wx, us* Wf){
  int i = blockIdx.x*256+threadIdx.x; if(i>=256000) return;
  int j=i&7; int m=(i>>3)&15; int kg=(i>>7)&3; int ch=(i>>9)&1;
  int r=i>>10; int tap=r%125; int b=r/125;
  int c = ch*32 + kg*8 + j;
  float v = (m<13) ? Wx[((size_t)(b*13+m)*125+tap)*64 + c] : 0.f;
  Wf[i] = f2u(v);
}

// ---- Wrr2: MFMA A-fragments for k_rr ----
__global__ void k_rrfrag(const float* wf, us* Wrr2){
  int i = blockIdx.x*256+threadIdx.x; if(i>=27648) return;
  int j=i&7; int l=(i>>3)&63; int kg=(i>>9)&1; int td=i>>10;
  int m=l&15, g=l>>4;
  int c = kg*32 + g*8 + j;
  Wrr2[i] = f2u(wf[oWRR + (c*27+td)*16 + m]);
}

// ---- Winvx: m-split 8-way, atomic accumulate (Wix pre-zeroed) ----
__global__ void k_Winvx(const float* Winvf, const float* xw1, float* Wix){
  int i = blockIdx.x*256+threadIdx.x; if(i>=6272) return;
  int ms = blockIdx.y;
  int kk=i%49; int c=(i/49)&63; int b=i/3136;
  int m0=ms*74; int m1=m0+74; if(m1>588) m1=588;
  const float* xp = xw1 + b*588*64 + c;
  float s=0;
  for(int m=m0;m<m1;m++) s += Winvf[kk*588+m] * xp[m*64];
  atomicAdd(&Wix[i], s);
}

// ---- x1t = bf16 channel-last (W_ct * x_CT + b), reads raw input ----
__global__ void k_x1(const void* xct_r, const int* flag, const float* wf, us* x1t){
  int p = blockIdx.x*256+threadIdx.x;
  int co0 = blockIdx.y*16; int b = blockIdx.z;
  float acc[16];
  #pragma unroll
  for(int o=0;o<16;o++) acc[o]=wf[oBCT+co0+o];
  int f=flag[0];
  if(f){
    const float* xp = (const float*)xct_r + (size_t)b*64*PP + p;
    for(int ci=0;ci<64;ci++){
      float xv = xp[(size_t)ci*PP];
      const float* w = wf + oWCT + ci*64 + co0;
      #pragma unroll
      for(int o=0;o<16;o++) acc[o] += w[o]*xv;
    }
  } else {
    const bf16* xp = (const bf16*)xct_r + (size_t)b*64*PP + p;
    for(int ci=0;ci<64;ci++){
      float xv = b2f(xp[(size_t)ci*PP]);
      const float* w = wf + oWCT + ci*64 + co0;
      #pragma unroll
      for(int o=0;o<16;o++) acc[o] += w[o]*xv;
    }
  }
  unsigned int pk[8];
  #pragma unroll
  for(int o2=0;o2<8;o2++)
    pk[o2] = (unsigned)f2u(acc[2*o2]) | ((unsigned)f2u(acc[2*o2+1])<<16);
  us* xo = x1t + ((size_t)(b*PP)+p)*64 + co0;
  *(uint4*)xo     = make_uint4(pk[0],pk[1],pk[2],pk[3]);
  *(uint4*)(xo+8) = make_uint4(pk[4],pk[5],pk[6],pk[7]);
}

// ---- Att = sigmoid(conv5x5x5) via MFMA implicit GEMM ----
__global__ __launch_bounds__(256) void k_att(const us* x1t, const us* Wf, float* att){
  __shared__ short xt[10368];
  int tid=threadIdx.x;
  int tile=blockIdx.x, t=blockIdx.y, b=blockIdx.z;
  int y0=(tile/7)*8, x0=(tile%7)*8;
  int w=tid>>6, l=tid&63;
  int pc=l&7, pr=(l>>3)&1, g=l>>4;
  f32x4 acc0={0,0,0,0}, acc1={0,0,0,0};
  int bbase = ((2*w+pr)*12 + pc)*72 + g*8;
  const us* Wb = Wf + (size_t)b*128000 + l*8;
  for(int dt=0;dt<5;dt++){
    int ti=t+dt-2;
    if(ti<0||ti>=8) continue;
    __syncthreads();
    for(int e=tid;e<1152;e+=256){
      int px=e>>3, q=e&7;
      int row=px/12, col=px-row*12;
      int gy=y0+row-2, gx=x0+col-2;
      uint4 v={0,0,0,0};
      if((unsigned)gy<56u && (unsigned)gx<56u)
        v = *(const uint4*)(x1t + ((size_t)(b*PP) + ti*3136 + gy*56 + gx)*64 + q*8);
      *(uint4*)&xt[px*72 + q*8] = v;
    }
    __syncthreads();
    const us* Wd = Wb + dt*25600;
    #pragma unroll
    for(int dy=0;dy<5;dy++){
      #pragma unroll
      for(int dx=0;dx<5;dx++){
        int off = bbase + dy*864 + dx*72;
        short8v a0 = *(const short8v*)(Wd + (dy*5+dx)*1024);
        short8v b0 = *(const short8v*)&xt[off];
        acc0 = __builtin_amdgcn_mfma_f32_16x16x32_bf16(a0,b0,acc0,0,0,0);
        short8v a1 = *(const short8v*)(Wd + (dy*5+dx)*1024 + 512);
        short8v b1 = *(const short8v*)&xt[off+32];
        acc1 = __builtin_amdgcn_mfma_f32_16x16x32_bf16(a1,b1,acc1,0,0,0);
      }
    }
  }
  int px=l&15; int epc=px&7, epr=px>>3;
  size_t pbase=(size_t)t*3136+(size_t)(y0+2*w+epr)*56+x0+epc;
  #pragma unroll
  for(int r=0;r<4;r++){
    int o=g*4+r;
    if(o<13){
      float s=acc0[r]+acc1[r];
      att[((size_t)b*13+o)*PP+pbase]=1.f/(1.f+__expf(-s));
    }
  }
}

// ---- kern49 = Winvx * x1 + b_inv (bf16 output) ----
__global__ void k_kern(const us* x1t, const float* Wix, const float* wf, bf16* kern){
  int p = blockIdx.x*256+threadIdx.x; int b=blockIdx.y;
  float acc[49];
  #pragma unroll
  for(int kk=0;kk<49;kk++) acc[kk]=wf[oBINV+kk];
  const us* xp = x1t + ((size_t)b*PP + p)*64;
  #pragma unroll
  for(int c8=0;c8<8;c8++){
    uint4 v = *(const uint4*)(xp + c8*8);
    const us* vp=(const us*)&v;
    #pragma unroll
    for(int j=0;j<8;j++){
      float xv = u2f(vp[j]);
      const float* w = Wix + (b*64+c8*8+j)*49;
      #pragma unroll
      for(int kk=0;kk<49;kk++) acc[kk]+=w[kk]*xv;
    }
  }
  bf16* out = kern + (size_t)b*49*PP + p;
  #pragma unroll
  for(int kk=0;kk<49;kk++) out[(size_t)kk*PP]=f2b(acc[kk]);
}

// ---- xw3 = conv3x3x3 via MFMA implicit GEMM ----
__global__ __launch_bounds__(256) void k_rr(const us* xwt, const us* Wrr2, bf16* xw3){
  __shared__ short xt[7200];
  int tid=threadIdx.x;
  int tile=blockIdx.x, d=blockIdx.y, b=blockIdx.z;
  int y0=(tile/7)*8, x0=(tile%7)*8;
  int w=tid>>6, l=tid&63;
  int pc=l&7, pr=(l>>3)&1, g=l>>4;
  f32x4 acc0={0,0,0,0}, acc1={0,0,0,0};
  int bbase = ((2*w+pr)*10 + pc)*72 + g*8;
  const us* Wl = Wrr2 + l*8;
  for(int dz=0;dz<3;dz++){
    int di=d+dz-1;
    if(di<0||di>=12) continue;
    __syncthreads();
    for(int e=tid;e<800;e+=256){
      int px=e>>3, q=e&7;
      int row=px/10, col=px-row*10;
      int gy=y0+row-1, gx=x0+col-1;
      uint4 v={0,0,0,0};
      if((unsigned)gy<56u && (unsigned)gx<56u)
        v = *(const uint4*)(xwt + ((size_t)(b*12+di)*3136 + gy*56 + gx)*64 + q*8);
      *(uint4*)&xt[px*72 + q*8] = v;
    }
    __syncthreads();
    const us* Wd = Wl + dz*9216;
    #pragma unroll
    for(int tap=0;tap<9;tap++){
      int dy=tap/3, dx=tap-dy*3;
      int off = bbase + (dy*10+dx)*72;
      short8v a0 = *(const short8v*)(Wd + tap*1024);
      short8v b0 = *(const short8v*)&xt[off];
      acc0 = __builtin_amdgcn_mfma_f32_16x16x32_bf16(a0,b0,acc0,0,0,0);
      short8v a1 = *(const short8v*)(Wd + tap*1024 + 512);
      short8v b1 = *(const short8v*)&xt[off+32];
      acc1 = __builtin_amdgcn_mfma_f32_16x16x32_bf16(a1,b1,acc1,0,0,0);
    }
  }
  int px=l&15; int epc=px&7, epr=px>>3;
  size_t pp=(size_t)(y0+2*w+epr)*56 + x0+epc;
  #pragma unroll
  for(int r=0;r<4;r++){
    int o=g*4+r;
    xw3[((size_t)(b*16+o)*12+d)*3136 + pp] = f2b(acc0[r]+acc1[r]);
  }
}

// ---- xattT = channel-last x_Att [b][p][256] (reads raw xct) ----
__global__ void k_xatt(const void* xct_r, const int* flag, const bf16* xw3,
                       const float* att, us* xattT){
  __shared__ us tl[64*258];
  int tid=threadIdx.x; int p0=blockIdx.x*64; int b=blockIdx.y;
  int f=flag[0];
  for(int k=0;k<64;k++){
    int idx=k*256+tid; int ch=idx>>6, pp=idx&63;
    int p=p0+pp;
    float v;
    if(ch<64){
      long ix = (long)(b*64+ch)*PP+p;
      float xv;
      if(f) xv = ((const float*)xct_r)[ix]; else xv = b2f(((const bf16*)xct_r)[ix]);
      v = xv * (1.f+att[(size_t)b*13*PP+p]);
    } else {
      int q=ch-64; int co=q/12, dd=q-co*12;
      int s=p%3136;
      v = b2f(xw3[((size_t)(b*16+co)*12+dd)*3136+s]) * (1.f+att[((size_t)b*13+1+q/16)*PP+p]);
    }
    tl[pp*258+ch]=f2u(v);
  }
  __syncthreads();
  for(int k=0;k<64;k++)
    xattT[((size_t)b*PP + p0+k)*256 + tid] = tl[k*258+tid];
}

// ---- y1T = x_Att @ W_p1^T ; LDS-staged weight panel in fragment order ----
__global__ __launch_bounds__(256) void k_p1(const us* xattT, const us* Wp1b, us* y1T){
  __shared__ us wt[16384];
  int tid=threadIdx.x; int w=tid>>6, l=tid&63;
  int pt=blockIdx.x, qtr=blockIdx.y, b=blockIdx.z;
  int co0 = qtr*64;
  #pragma unroll
  for(int it=0;it<8;it++){
    int f = it*256+tid;
    int n=f>>9, kc=(f>>6)&7, lane=f&63;
    int co = co0 + n*16 + (lane&15);
    int ci = (lane>>4)*8 + kc*32;
    uint4 v = *(const uint4*)(Wp1b + (size_t)co*256 + ci);
    *(uint4*)(wt + f*8) = v;
  }
  __syncthreads();
  int p0 = pt*64 + w*16;
  const us* xa = xattT + ((size_t)b*PP + p0 + (l&15))*256 + ((l>>4)*8);
  f32x4 acc[4];
  #pragma unroll
  for(int n=0;n<4;n++) acc[n]=(f32x4){0,0,0,0};
  for(int kc=0;kc<8;kc++){
    short8v a = *(const short8v*)(xa + kc*32);
    #pragma unroll
    for(int n=0;n<4;n++){
      short8v bf = *(const short8v*)(wt + ((n*8+kc)*64 + l)*8);
      acc[n] = __builtin_amdgcn_mfma_f32_16x16x32_bf16(a,bf,acc[n],0,0,0);
    }
  }
  int col=l&15, rowb=(l>>4)*4;
  us* yo = y1T + ((size_t)b*PP + p0)*256 + co0;
  #pragma unroll
  for(int n=0;n<4;n++)
    #pragma unroll
    for(int r=0;r<4;r++)
      yo[(size_t)(rowb+r)*256 + n*16 + col] = f2u(acc[n][r]);
}

// ---- per-channel sum/sumsq over channel-last [b][p][256] ----
__global__ void k_stats(const us* src, float* sum, float* sq){
  int tid=threadIdx.x; int pt=blockIdx.x, b=blockIdx.y;
  const us* p = src + ((size_t)b*PP + pt*64)*256 + tid;
  float s=0,q=0;
  #pragma unroll 8
  for(int i=0;i<64;i++){ float v=u2f(p[(size_t)i*256]); s+=v; q+=v*v; }
  atomicAdd(&sum[tid],s); atomicAdd(&sq[tid],q);
}
__global__ void k_finstat(const float* sum, const float* sq, const void* g, const void* be,
                          const int* flag, float* sc, float* sh){
  int ch=threadIdx.x;
  int f=flag[0];
  float m = sum[ch]*(1.f/50176.f);
  float v = sq[ch]*(1.f/50176.f) - m*m;
  float s = ldin(g,ch,f) * rsqrtf(v+1e-5f);
  sc[ch]=s; sh[ch]=ldin(be,ch,f) - m*s;
}

// ---- involution, bn1+relu fused into staging; bf16 kern ----
__global__ __launch_bounds__(256) void k_inv(const us* y1T, const float* sc1, const float* sh1,
                                             const bf16* kern, us* invT){
  __shared__ __align__(16) us xt[196*72];
  int tid=threadIdx.x;
  int bx=blockIdx.x, by=blockIdx.y, bz=blockIdx.z;
  int t=bz&7, b=bz>>3;
  int y0=(bx/7)*8, x0=(bx%7)*8, c0=by*64;
  int w=tid>>6, l=tid&63;
  int ty=l>>3, tx=l&7;
  int segb = c0 + (tid&7)*8;
  float scr[8], shr[8];
  #pragma unroll
  for(int j=0;j<8;j++){ scr[j]=sc1[segb+j]; shr[j]=sh1[segb+j]; }
  for(int e=tid;e<1568;e+=256){
    int row=e>>3, seg=e&7;                       // seg == tid&7
    int yy=row/14, xx=row%14;
    int gy=y0+yy-3, gx=x0+xx-3;
    uint4 o4={0,0,0,0};
    if(gy>=0&&gy<56&&gx>=0&&gx<56){
      uint4 v = *(const uint4*)&y1T[((size_t)b*PP + t*3136 + gy*56+gx)*256 + c0 + seg*8];
      const us* vp=(const us*)&v;
      us r[8];
      #pragma unroll
      for(int j=0;j<8;j++){
        float x = u2f(vp[j]);
        x = x*scr[j]+shr[j]; x = x>0.f?x:0.f;
        r[j]=f2u(x);
      }
      o4 = *(const uint4*)r;
    }
    *(uint4*)&xt[row*72+seg*8]=o4;
  }
  float kr[49];
  size_t pxs=(size_t)t*3136 + (y0+ty)*56 + x0+tx;
  #pragma unroll
  for(int kk=0;kk<49;kk++) kr[kk]=b2f(kern[((size_t)b*49+kk)*PP+pxs]);
  __syncthreads();
  #pragma unroll
  for(int s=0;s<2;s++){
    int sub=2*w+s;
    float acc[8];
    #pragma unroll
    for(int e=0;e<8;e++) acc[e]=0;
    for(int i=0;i<7;i++){
      #pragma unroll
      for(int j=0;j<7;j++){
        uint4 u = *(const uint4*)&xt[((ty+i)*14+tx+j)*72 + sub*8];
        float kv = kr[i*7+j];
        acc[0]+=kv*blo(u.x); acc[1]+=kv*bhi(u.x);
        acc[2]+=kv*blo(u.y); acc[3]+=kv*bhi(u.y);
        acc[4]+=kv*blo(u.z); acc[5]+=kv*bhi(u.z);
        acc[6]+=kv*blo(u.w); acc[7]+=kv*bhi(u.w);
      }
    }
    unsigned pk[4];
    #pragma unroll
    for(int e=0;e<4;e++)
      pk[e] = (unsigned)f2u(acc[2*e]) | ((unsigned)f2u(acc[2*e+1])<<16);
    *(uint4*)&invT[((size_t)b*PP+pxs)*256 + c0 + sub*8] = make_uint4(pk[0],pk[1],pk[2],pk[3]);
  }
}

// ---- W2s = W_p2*diag(sc2) bf16; bias2 = b_p2 + W_p2@sh2 ----
__global__ void k_w2s(const float* wf, const float* sc2, const float* sh2,
                      us* W2sb, float* bias2){
  __shared__ float red[256];
  int o=blockIdx.x, ci=threadIdx.x;
  float wv = wf[oWP2 + ci*64 + o];
  W2sb[o*256+ci] = f2u(wv * sc2[ci]);
  red[ci] = wv * sh2[ci];
  __syncthreads();
  for(int st=128;st>0;st>>=1){ if(ci<st) red[ci]+=red[ci+st]; __syncthreads(); }
  if(ci==0) bias2[o] = wf[oBP2+o] + red[0];
}

// ---- out = W2s@invT + W_p2@xattT + bias2 ; both weight panels LDS-staged ----
__global__ __launch_bounds__(256) void k_final(const us* invT, const us* xattT,
                                               const us* W2sb, const us* Wp2b,
                                               const float* bias2, float* out){
  __shared__ us wt[32768];
  int tid=threadIdx.x; int w=tid>>6, l=tid&63;
  int pt=blockIdx.x, b=blockIdx.y;
  #pragma unroll
  for(int it=0;it<16;it++){
    int f = it*256+tid;
    int which = f>>11;
    int g = f&2047;
    int n=g>>9, kc=(g>>6)&7, lane=g&63;
    int co = n*16 + (lane&15);
    int ci = (lane>>4)*8 + kc*32;
    const us* src = which ? Wp2b : W2sb;
    uint4 v = *(const uint4*)(src + (size_t)co*256 + ci);
    *(uint4*)(wt + f*8) = v;
  }
  __syncthreads();
  int p0 = pt*64 + w*16;
  size_t abase = ((size_t)b*PP + p0 + (l&15))*256 + ((l>>4)*8);
  f32x4 acc[4];
  #pragma unroll
  for(int n=0;n<4;n++) acc[n]=(f32x4){0,0,0,0};
  for(int kc=0;kc<8;kc++){
    short8v ai = *(const short8v*)(invT + abase + kc*32);
    short8v ax = *(const short8v*)(xattT + abase + kc*32);
    #pragma unroll
    for(int n=0;n<4;n++){
      short8v b1 = *(const short8v*)(wt + ((n*8+kc)*64 + l)*8);
      acc[n] = __builtin_amdgcn_mfma_f32_16x16x32_bf16(ai,b1,acc[n],0,0,0);
      short8v b2 = *(const short8v*)(wt + 16384 + ((n*8+kc)*64 + l)*8);
      acc[n] = __builtin_amdgcn_mfma_f32_16x16x32_bf16(ax,b2,acc[n],0,0,0);
    }
  }
  int col=l&15, rowb=(l>>4)*4;
  #pragma unroll
  for(int n=0;n<4;n++){
    float bb = bias2[n*16+col];
    #pragma unroll
    for(int r=0;r<4;r++)
      out[((size_t)b*64 + n*16+col)*PP + p0 + rowb + r] = acc[n][r] + bb;
  }
}

extern "C" void kernel_launch(void* const* d_in, const int* in_sizes, int n_in,
                              void* d_out, int out_size, void* d_ws, size_t ws_size,
                              hipStream_t stream){
  const void* xct_r =d_in[0];
  const void* xwsi_r=d_in[1];
  const void* Wct =d_in[2];
  const void* bct =d_in[3];
  const void* Wwsi=d_in[4];
  const void* bwsi=d_in[5];
  const void* Watt=d_in[6];
  const void* Winv=d_in[7];
  const void* binv=d_in[8];
  const void* Wrr =d_in[9];
  const void* g1  =d_in[10];
  const void* be1 =d_in[11];
  const void* g2  =d_in[12];
  const void* be2 =d_in[13];
  const void* Wp1 =d_in[14];
  const void* Wp2 =d_in[16];
  const void* bp2 =d_in[17];
  float* ws=(float*)d_ws;
  float* xw1=ws+XW1o;
  float* Wx=ws+WXo; float* Wix=ws+WIXo;
  float* att=ws+ATTo;
  bf16* kern=(bf16*)(ws+KERNo);
  us* Wf=(us*)(ws+WXTo);
  us* Wrr2=(us*)(ws+WRR2o);
  bf16* xw3=(bf16*)(ws+XW3o);
  float* stat=ws+STATo; float* wf=ws+WFo;
  float* Wattf=ws+WATTFo; float* Winvf=ws+WINVFo;
  float* bias2=ws+WATTFo;     // aliases Wattf (dead after k_Wx)
  int* flag=(int*)(ws+FLAGo);
  bf16* bfb=(bf16*)(ws+BF16o);
  us* x1t=(us*)(bfb+bX1T);
  us* xattT=(us*)(bfb+bXATT); us* y1T=(us*)(bfb+bY1); us* invT=(us*)(bfb+bINV);
  us* Wp1b=(us*)(bfb+bWP1B); us* Wp2b=(us*)(bfb+bWP2B); us* W2sb=(us*)(bfb+bW2S);
  us* xwt=(us*)(bfb+bXWT);
  float* sum1=stat; float* sq1=stat+256; float* sum2=stat+512; float* sq2=stat+768;
  float* sc1=stat+1024; float* sh1=stat+1280; float* sc2=stat+1536; float* sh2=stat+1792;

  hipMemsetAsync(stat,0,4096,stream);
  hipMemsetAsync(Wix,0,6272*4,stream);
  k_detect<<<1,64,0,stream>>>((const us*)xct_r,flag);
  k_prep  <<<3733,256,0,stream>>>(Watt,Winv,Wct,bct,Wwsi,bwsi,Wrr,binv,Wp1,Wp2,bp2,
                                  Wattf,Winvf,wf,Wp1b,Wp2b,flag);
  k_wsit  <<<dim3(49,12,2),256,0,stream>>>(xwsi_r,flag,xwt); // xwt aliases y1T head
  k_poolxw1<<<dim3(588,2),64,0,stream>>>(xwt,wf,xw1);
  k_Wx    <<<813,256,0,stream>>>(Wattf,xw1,Wx);
  k_Wfrag <<<1000,256,0,stream>>>(Wx,Wf);
  k_rrfrag<<<108,256,0,stream>>>(wf,Wrr2);                   // overwrites Wx head (dead)
  k_Winvx <<<dim3(25,8),256,0,stream>>>(Winvf,xw1,Wix);
  k_x1    <<<dim3(98,4,2),256,0,stream>>>(xct_r,flag,wf,x1t);
  k_att   <<<dim3(49,8,2),256,0,stream>>>(x1t,Wf,att);
  k_kern  <<<dim3(98,2),256,0,stream>>>(x1t,Wix,wf,kern);
  k_rr    <<<dim3(49,12,2),256,0,stream>>>(xwt,Wrr2,xw3);
  k_xatt  <<<dim3(392,2),256,0,stream>>>(xct_r,flag,xw3,att,xattT);
  k_p1    <<<dim3(392,4,2),256,0,stream>>>(xattT,Wp1b,y1T);  // overwrites xwt (dead)
  k_stats <<<dim3(392,2),256,0,stream>>>(y1T,sum1,sq1);
  k_finstat<<<1,256,0,stream>>>(sum1,sq1,g1,be1,flag,sc1,sh1);
  k_inv   <<<dim3(49,4,16),256,0,stream>>>(y1T,sc1,sh1,kern,invT);
  k_stats <<<dim3(392,2),256,0,stream>>>(invT,sum2,sq2);
  k_finstat<<<1,256,0,stream>>>(sum2,sq2,g2,be2,flag,sc2,sh2);
  k_w2s   <<<64,256,0,stream>>>(wf,sc2,sh2,W2sb,bias2);
  k_final <<<dim3(392,2),256,0,stream>>>(invT,xattT,W2sb,Wp2b,bias2,(float*)d_out);
}

// Round 19
// 364.066 us; speedup vs baseline: 1.9102x; 1.0078x over previous
//
#include <hip/hip_runtime.h>
#include <hip/hip_bf16.h>
#include <math.h>

typedef __hip_bfloat16 bf16;
typedef unsigned short us;
typedef __attribute__((ext_vector_type(8))) short short8v;
typedef __attribute__((ext_vector_type(4))) float f32x4;
#define DEV static __device__ __forceinline__
DEV float b2f(bf16 x){ return __bfloat162float(x); }
DEV bf16  f2b(float x){ return __float2bfloat16(x); }
DEV us    f2u(float x){ bf16 h=f2b(x); return *(us*)&h; }
DEV float u2f(us u){ return __uint_as_float(((unsigned)u)<<16); }
DEV float blo(unsigned int w){ return __uint_as_float(w<<16); }
DEV float bhi(unsigned int w){ return __uint_as_float(w&0xffff0000u); }
DEV float ldin(const void* p, long i, int f){
  return f ? ((const float*)p)[i] : b2f(((const bf16*)p)[i]);
}

// problem dims
#define PP 25088            // t*h*w = 8*56*56

// ws layout (float units)
#define POOLo  3211264L
#define XW1o   3286528L
#define WXo    3361792L     // Wx f32 208000; re-aliased by Wrr2 after k_Wfrag
#define WXTo   3569792L     // Wf MFMA A-frags: 256000 bf16
#define WIXo   3825792L
#define ATTo   3832064L     // 2*13*25088 f32
#define KERNo  4484352L     // kern bf16 [b][kk][p]
#define XW3o   6942976L     // xw3 bf16
#define STATo  8147200L
#define FLAGo  8149248L
#define WFo    8149264L
#define WATTFo 8267280L     // W_att f32; dead after k_Wx -> bias2 aliases head
#define WINVFo 9222784L
#define BF16o  9251600L
#define WRR2o  WXo
// bf16 sub-offsets (bf16 element units)
#define bX1T   3211264L     // x1t [b][p][64] 3211264
#define bXATT  8028160L     // xattT [b][p][256] 12845056
#define bY1    20873216L    // y1T [b][p][256] 12845056 (xwt aliases head until k_p1)
#define bINV   33718272L    // invT [b][p][256] 12845056
#define bWP1B  46563328L    // Wp1b bf16 raw [co][ci] 65536
#define bWP2B  46628864L    // Wp2b bf16 raw [o][ci] 16384
#define bW2S   46645248L    // W2sb bf16 [o][ci] 16384
#define bWCTB  46661632L    // Wctb bf16 raw [co][ci] 4096
#define bXWT   bY1          // xwt [b][d][hw][64]; dead before k_p1 writes y1T
// wf sub-offsets
#define oWCT   0
#define oBCT   4096
#define oWWSI  4160
#define oBWSI  8256
#define oWRR   8320
#define oBINV  35968
#define oWP1   36032
#define oWP2   101568       // [ci][co] 256x64
#define oBP2   117952

// ---- input dtype probe ----
__global__ void k_detect(const us* raw, int* flag){
  int t = threadIdx.x;
  us u = raw[2*t];
  int e = (u>>7)&0xFF;
  int hit = (e >= 137);
  unsigned long long m = __ballot(hit);
  if(t==0) flag[0] = (__popcll(m) >= 8) ? 1 : 0;
}

// ---- merged weight prep: Wattf, Winvf, wf, Wp1b, Wp2b, Wctb ----
__global__ void k_prep(const void* Watt,const void* Winv,const void* Wct,const void* bct,
                       const void* Wwsi,const void* bwsi,const void* Wrr,const void* binv,
                       const void* Wp1,const void* Wp2,const void* bp2,
                       float* Wattf,float* Winvf,float* wf,us* Wp1b,us* Wp2b,us* Wctb,
                       const int* flag){
  int i = blockIdx.x*256 + threadIdx.x;
  int f = flag[0];
  if(i<955500) Wattf[i]=ldin(Watt,i,f);
  if(i<28812)  Winvf[i]=ldin(Winv,i,f);
  if(i<65536)  Wp1b[i]=f2u(ldin(Wp1,i,f));
  else if(i<81920) Wp2b[i-65536]=f2u(ldin(Wp2,i-65536,f));
  if(i<4096)   Wctb[i]=f2u(ldin(Wct,i,f));
  if (i < 4096){ int co=i>>6, ci=i&63; wf[oWCT + ci*64+co] = ldin(Wct,i,f); }
  else if (i < 4160){ wf[i] = ldin(bct,i-4096,f); }
  else if (i < 8256){ wf[i] = ldin(Wwsi,i-4160,f); }
  else if (i < 8320){ wf[i] = ldin(bwsi,i-8256,f); }
  else if (i < 35968){ int l=i-8320; int co=l/1728, r=l%1728, ci=r/27, tp=r%27;
                       wf[oWRR + (ci*27+tp)*16+co] = ldin(Wrr,l,f); }
  else if (i < 36017){ wf[oBINV + (i-35968)] = ldin(binv,i-35968,f); }
  else if (i < 36032){ }
  else if (i < 118016){
    int l=i-36032;
    if(l<65536){ int co=l>>8, ci=l&255; wf[oWP1 + ci*256+co] = ldin(Wp1,l,f); }
    else if(l<81920){ int l2=l-65536; int o=l2>>8, ci=l2&255; wf[oWP2 + ci*64+o] = ldin(Wp2,l2,f); }
    else if(l<81984){ wf[oBP2 + (l-81920)] = ldin(bp2,l-81920,f); }
  }
}

// ---- xwt = channel-last x_WSI [b][d][hw][64] straight from raw input ----
__global__ void k_wsit(const void* xwsi_r, const int* flag, us* xwt){
  __shared__ us tl[64*68];
  int tid=threadIdx.x; int p0=blockIdx.x*64; int d=blockIdx.y; int b=blockIdx.z;
  int f=flag[0];
  #pragma unroll
  for(int k=0;k<16;k++){
    int idx=k*256+tid; int px=idx&63, c=idx>>6;
    float v = ldin(xwsi_r, ((long)(b*64+c)*12+d)*3136 + p0+px, f);
    tl[px*68+c] = f2u(v);
  }
  __syncthreads();
  #pragma unroll
  for(int k=0;k<16;k++){
    int idx=k*256+tid; int px=idx>>6, ch=idx&63;
    xwt[((size_t)(b*12+d)*3136 + p0+px)*64 + ch] = tl[px*68+ch];
  }
}

// ---- fused adaptive-pool + xw1 (one block per (m,b), 64 threads) ----
__global__ __launch_bounds__(64) void k_poolxw1(const us* xwt, const float* wf, float* xw1){
  __shared__ float pl[64];
  int c=threadIdx.x; int m=blockIdx.x; int b=blockIdx.y;
  int d=m/49, r=m%49, ii=r/7, jj=r%7;
  const us* src = xwt + ((size_t)(b*12+d)*3136 + (ii*8)*56 + jj*8)*64 + c;
  float s=0;
  #pragma unroll
  for(int u=0;u<8;u++)
    #pragma unroll
    for(int v=0;v<8;v++) s += u2f(src[(size_t)(u*56+v)*64]);
  pl[c] = s*(1.f/64.f);
  __syncthreads();
  const float* w = wf + oWWSI + c*64;
  float o = wf[oBWSI + c];
  for(int ci=0;ci<64;ci++) o += w[ci]*pl[ci];
  xw1[(b*588+m)*64+c] = o;
}

// ---- Wx[b,o,tap,c] = sum_m W_att[o,m,tap] * xw1[b,c,m] ----
__global__ void k_Wx(const float* Wattf, const float* xw1, float* Wx){
  int i = blockIdx.x*256+threadIdx.x; if(i>=208000) return;
  int c=i&63; int r=i>>6; int tap=r%125; int o=(r/125)%13; int b=r/1625;
  const float* wa = Wattf + (size_t)o*588*125 + tap;
  const float* xp = xw1 + b*588*64 + c;
  float s=0;
  for(int m=0;m<588;m++) s += wa[(size_t)m*125] * xp[m*64];
  Wx[i]=s;
}

// ---- Wf: MFMA A-fragments for k_att ----
__global__ void k_Wfrag(const float* Wx, us* Wf){
  int i = blockIdx.x*256+threadIdx.x; if(i>=256000) return;
  int j=i&7; int m=(i>>3)&15; int kg=(i>>7)&3; int ch=(i>>9)&1;
  int r=i>>10; int tap=r%125; int b=r/125;
  int c = ch*32 + kg*8 + j;
  float v = (m<13) ? Wx[((size_t)(b*13+m)*125+tap)*64 + c] : 0.f;
  Wf[i] = f2u(v);
}

// ---- Wrr2: MFMA A-fragments for k_rr ----
__global__ void k_rrfrag(const float* wf, us* Wrr2){
  int i = blockIdx.x*256+threadIdx.x; if(i>=27648) return;
  int j=i&7; int l=(i>>3)&63; int kg=(i>>9)&1; int td=i>>10;
  int m=l&15, g=l>>4;
  int c = kg*32 + g*8 + j;
  Wrr2[i] = f2u(wf[oWRR + (c*27+td)*16 + m]);
}

// ---- Winvx: m-split 8-way, atomic accumulate (Wix pre-zeroed) ----
__global__ void k_Winvx(const float* Winvf, const float* xw1, float* Wix){
  int i = blockIdx.x*256+threadIdx.x; if(i>=6272) return;
  int ms = blockIdx.y;
  int kk=i%49; int c=(i/49)&63; int b=i/3136;
  int m0=ms*74; int m1=m0+74; if(m1>588) m1=588;
  const float* xp = xw1 + b*588*64 + c;
  float s=0;
  for(int m=m0;m<m1;m++) s += Winvf[kk*588+m] * xp[m*64];
  atomicAdd(&Wix[i], s);
}

// ---- x1t = bf16 channel-last (W_ct @ x_CT + b) via MFMA GEMM ----
// block: 64 px, 4 waves x 16 px; LDS transpose then M=px, N=64co, K=64ci
__global__ __launch_bounds__(256) void k_x1(const void* xct_r, const int* flag, const float* wf,
                                            const us* Wctb, us* x1t){
  __shared__ us tl[64*72];
  int tid=threadIdx.x; int w=tid>>6, l=tid&63;
  int pt=blockIdx.x, b=blockIdx.y;
  int p0=pt*64;
  int f=flag[0];
  #pragma unroll
  for(int k=0;k<16;k++){
    int idx=k*256+tid; int ch=idx>>6, pp=idx&63;
    float v = ldin(xct_r, (long)(b*64+ch)*PP + p0+pp, f);
    tl[pp*72+ch] = f2u(v);
  }
  __syncthreads();
  const us* xa = tl + (w*16 + (l&15))*72 + ((l>>4)*8);
  f32x4 acc[4];
  #pragma unroll
  for(int n=0;n<4;n++) acc[n]=(f32x4){0,0,0,0};
  #pragma unroll
  for(int kc=0;kc<2;kc++){
    short8v a = *(const short8v*)(xa + kc*32);
    #pragma unroll
    for(int n=0;n<4;n++){
      short8v bf = *(const short8v*)(Wctb + (n*16+(l&15))*64 + kc*32 + ((l>>4)*8));
      acc[n] = __builtin_amdgcn_mfma_f32_16x16x32_bf16(a,bf,acc[n],0,0,0);
    }
  }
  int col=l&15, rowb=(l>>4)*4;
  us* xo = x1t + ((size_t)b*PP + p0 + w*16)*64;
  #pragma unroll
  for(int n=0;n<4;n++){
    float bb = wf[oBCT + n*16 + col];
    #pragma unroll
    for(int r=0;r<4;r++)
      xo[(rowb+r)*64 + n*16 + col] = f2u(acc[n][r] + bb);
  }
}

// ---- Att = sigmoid(conv5x5x5) via MFMA implicit GEMM ----
__global__ __launch_bounds__(256) void k_att(const us* x1t, const us* Wf, float* att){
  __shared__ short xt[10368];
  int tid=threadIdx.x;
  int tile=blockIdx.x, t=blockIdx.y, b=blockIdx.z;
  int y0=(tile/7)*8, x0=(tile%7)*8;
  int w=tid>>6, l=tid&63;
  int pc=l&7, pr=(l>>3)&1, g=l>>4;
  f32x4 acc0={0,0,0,0}, acc1={0,0,0,0};
  int bbase = ((2*w+pr)*12 + pc)*72 + g*8;
  const us* Wb = Wf + (size_t)b*128000 + l*8;
  for(int dt=0;dt<5;dt++){
    int ti=t+dt-2;
    if(ti<0||ti>=8) continue;
    __syncthreads();
    for(int e=tid;e<1152;e+=256){
      int px=e>>3, q=e&7;
      int row=px/12, col=px-row*12;
      int gy=y0+row-2, gx=x0+col-2;
      uint4 v={0,0,0,0};
      if((unsigned)gy<56u && (unsigned)gx<56u)
        v = *(const uint4*)(x1t + ((size_t)(b*PP) + ti*3136 + gy*56 + gx)*64 + q*8);
      *(uint4*)&xt[px*72 + q*8] = v;
    }
    __syncthreads();
    const us* Wd = Wb + dt*25600;
    #pragma unroll
    for(int dy=0;dy<5;dy++){
      #pragma unroll
      for(int dx=0;dx<5;dx++){
        int off = bbase + dy*864 + dx*72;
        short8v a0 = *(const short8v*)(Wd + (dy*5+dx)*1024);
        short8v b0 = *(const short8v*)&xt[off];
        acc0 = __builtin_amdgcn_mfma_f32_16x16x32_bf16(a0,b0,acc0,0,0,0);
        short8v a1 = *(const short8v*)(Wd + (dy*5+dx)*1024 + 512);
        short8v b1 = *(const short8v*)&xt[off+32];
        acc1 = __builtin_amdgcn_mfma_f32_16x16x32_bf16(a1,b1,acc1,0,0,0);
      }
    }
  }
  int px=l&15; int epc=px&7, epr=px>>3;
  size_t pbase=(size_t)t*3136+(size_t)(y0+2*w+epr)*56+x0+epc;
  #pragma unroll
  for(int r=0;r<4;r++){
    int o=g*4+r;
    if(o<13){
      float s=acc0[r]+acc1[r];
      att[((size_t)b*13+o)*PP+pbase]=1.f/(1.f+__expf(-s));
    }
  }
}

// ---- kern49 = Winvx * x1 + b_inv (bf16 output) ----
__global__ void k_kern(const us* x1t, const float* Wix, const float* wf, bf16* kern){
  int p = blockIdx.x*256+threadIdx.x; int b=blockIdx.y;
  float acc[49];
  #pragma unroll
  for(int kk=0;kk<49;kk++) acc[kk]=wf[oBINV+kk];
  const us* xp = x1t + ((size_t)b*PP + p)*64;
  #pragma unroll
  for(int c8=0;c8<8;c8++){
    uint4 v = *(const uint4*)(xp + c8*8);
    const us* vp=(const us*)&v;
    #pragma unroll
    for(int j=0;j<8;j++){
      float xv = u2f(vp[j]);
      const float* w = Wix + (b*64+c8*8+j)*49;
      #pragma unroll
      for(int kk=0;kk<49;kk++) acc[kk]+=w[kk]*xv;
    }
  }
  bf16* out = kern + (size_t)b*49*PP + p;
  #pragma unroll
  for(int kk=0;kk<49;kk++) out[(size_t)kk*PP]=f2b(acc[kk]);
}

// ---- xw3 = conv3x3x3 via MFMA implicit GEMM ----
__global__ __launch_bounds__(256) void k_rr(const us* xwt, const us* Wrr2, bf16* xw3){
  __shared__ short xt[7200];
  int tid=threadIdx.x;
  int tile=blockIdx.x, d=blockIdx.y, b=blockIdx.z;
  int y0=(tile/7)*8, x0=(tile%7)*8;
  int w=tid>>6, l=tid&63;
  int pc=l&7, pr=(l>>3)&1, g=l>>4;
  f32x4 acc0={0,0,0,0}, acc1={0,0,0,0};
  int bbase = ((2*w+pr)*10 + pc)*72 + g*8;
  const us* Wl = Wrr2 + l*8;
  for(int dz=0;dz<3;dz++){
    int di=d+dz-1;
    if(di<0||di>=12) continue;
    __syncthreads();
    for(int e=tid;e<800;e+=256){
      int px=e>>3, q=e&7;
      int row=px/10, col=px-row*10;
      int gy=y0+row-1, gx=x0+col-1;
      uint4 v={0,0,0,0};
      if((unsigned)gy<56u && (unsigned)gx<56u)
        v = *(const uint4*)(xwt + ((size_t)(b*12+di)*3136 + gy*56 + gx)*64 + q*8);
      *(uint4*)&xt[px*72 + q*8] = v;
    }
    __syncthreads();
    const us* Wd = Wl + dz*9216;
    #pragma unroll
    for(int tap=0;tap<9;tap++){
      int dy=tap/3, dx=tap-dy*3;
      int off = bbase + (dy*10+dx)*72;
      short8v a0 = *(const short8v*)(Wd + tap*1024);
      short8v b0 = *(const short8v*)&xt[off];
      acc0 = __builtin_amdgcn_mfma_f32_16x16x32_bf16(a0,b0,acc0,0,0,0);
      short8v a1 = *(const short8v*)(Wd + tap*1024 + 512);
      short8v b1 = *(const short8v*)&xt[off+32];
      acc1 = __builtin_amdgcn_mfma_f32_16x16x32_bf16(a1,b1,acc1,0,0,0);
    }
  }
  int px=l&15; int epc=px&7, epr=px>>3;
  size_t pp=(size_t)(y0+2*w+epr)*56 + x0+epc;
  #pragma unroll
  for(int r=0;r<4;r++){
    int o=g*4+r;
    xw3[((size_t)(b*16+o)*12+d)*3136 + pp] = f2b(acc0[r]+acc1[r]);
  }
}

// ---- xattT = channel-last x_Att [b][p][256] (reads raw xct) ----
__global__ void k_xatt(const void* xct_r, const int* flag, const bf16* xw3,
                       const float* att, us* xattT){
  __shared__ us tl[64*258];
  int tid=threadIdx.x; int p0=blockIdx.x*64; int b=blockIdx.y;
  int f=flag[0];
  for(int k=0;k<64;k++){
    int idx=k*256+tid; int ch=idx>>6, pp=idx&63;
    int p=p0+pp;
    float v;
    if(ch<64){
      long ix = (long)(b*64+ch)*PP+p;
      float xv;
      if(f) xv = ((const float*)xct_r)[ix]; else xv = b2f(((const bf16*)xct_r)[ix]);
      v = xv * (1.f+att[(size_t)b*13*PP+p]);
    } else {
      int q=ch-64; int co=q/12, dd=q-co*12;
      int s=p%3136;
      v = b2f(xw3[((size_t)(b*16+co)*12+dd)*3136+s]) * (1.f+att[((size_t)b*13+1+q/16)*PP+p]);
    }
    tl[pp*258+ch]=f2u(v);
  }
  __syncthreads();
  for(int k=0;k<64;k++)
    xattT[((size_t)b*PP + p0+k)*256 + tid] = tl[k*258+tid];
}

// ---- y1T = x_Att @ W_p1^T ; LDS-staged weight panel in fragment order ----
__global__ __launch_bounds__(256) void k_p1(const us* xattT, const us* Wp1b, us* y1T){
  __shared__ us wt[16384];
  int tid=threadIdx.x; int w=tid>>6, l=tid&63;
  int pt=blockIdx.x, qtr=blockIdx.y, b=blockIdx.z;
  int co0 = qtr*64;
  #pragma unroll
  for(int it=0;it<8;it++){
    int f = it*256+tid;
    int n=f>>9, kc=(f>>6)&7, lane=f&63;
    int co = co0 + n*16 + (lane&15);
    int ci = (lane>>4)*8 + kc*32;
    uint4 v = *(const uint4*)(Wp1b + (size_t)co*256 + ci);
    *(uint4*)(wt + f*8) = v;
  }
  __syncthreads();
  int p0 = pt*64 + w*16;
  const us* xa = xattT + ((size_t)b*PP + p0 + (l&15))*256 + ((l>>4)*8);
  f32x4 acc[4];
  #pragma unroll
  for(int n=0;n<4;n++) acc[n]=(f32x4){0,0,0,0};
  for(int kc=0;kc<8;kc++){
    short8v a = *(const short8v*)(xa + kc*32);
    #pragma unroll
    for(int n=0;n<4;n++){
      short8v bf = *(const short8v*)(wt + ((n*8+kc)*64 + l)*8);
      acc[n] = __builtin_amdgcn_mfma_f32_16x16x32_bf16(a,bf,acc[n],0,0,0);
    }
  }
  int col=l&15, rowb=(l>>4)*4;
  us* yo = y1T + ((size_t)b*PP + p0)*256 + co0;
  #pragma unroll
  for(int n=0;n<4;n++)
    #pragma unroll
    for(int r=0;r<4;r++)
      yo[(size_t)(rowb+r)*256 + n*16 + col] = f2u(acc[n][r]);
}

// ---- per-channel sum/sumsq over channel-last [b][p][256] ----
__global__ void k_stats(const us* src, float* sum, float* sq){
  int tid=threadIdx.x; int pt=blockIdx.x, b=blockIdx.y;
  const us* p = src + ((size_t)b*PP + pt*64)*256 + tid;
  float s=0,q=0;
  #pragma unroll 8
  for(int i=0;i<64;i++){ float v=u2f(p[(size_t)i*256]); s+=v; q+=v*v; }
  atomicAdd(&sum[tid],s); atomicAdd(&sq[tid],q);
}
__global__ void k_finstat(const float* sum, const float* sq, const void* g, const void* be,
                          const int* flag, float* sc, float* sh){
  int ch=threadIdx.x;
  int f=flag[0];
  float m = sum[ch]*(1.f/50176.f);
  float v = sq[ch]*(1.f/50176.f) - m*m;
  float s = ldin(g,ch,f) * rsqrtf(v+1e-5f);
  sc[ch]=s; sh[ch]=ldin(be,ch,f) - m*s;
}

// ---- involution, bn1+relu fused into staging; bf16 kern ----
__global__ __launch_bounds__(256) void k_inv(const us* y1T, const float* sc1, const float* sh1,
                                             const bf16* kern, us* invT){
  __shared__ __align__(16) us xt[196*72];
  int tid=threadIdx.x;
  int bx=blockIdx.x, by=blockIdx.y, bz=blockIdx.z;
  int t=bz&7, b=bz>>3;
  int y0=(bx/7)*8, x0=(bx%7)*8, c0=by*64;
  int w=tid>>6, l=tid&63;
  int ty=l>>3, tx=l&7;
  int segb = c0 + (tid&7)*8;
  float scr[8], shr[8];
  #pragma unroll
  for(int j=0;j<8;j++){ scr[j]=sc1[segb+j]; shr[j]=sh1[segb+j]; }
  for(int e=tid;e<1568;e+=256){
    int row=e>>3, seg=e&7;                       // seg == tid&7
    int yy=row/14, xx=row%14;
    int gy=y0+yy-3, gx=x0+xx-3;
    uint4 o4={0,0,0,0};
    if(gy>=0&&gy<56&&gx>=0&&gx<56){
      uint4 v = *(const uint4*)&y1T[((size_t)b*PP + t*3136 + gy*56+gx)*256 + c0 + seg*8];
      const us* vp=(const us*)&v;
      us r[8];
      #pragma unroll
      for(int j=0;j<8;j++){
        float x = u2f(vp[j]);
        x = x*scr[j]+shr[j]; x = x>0.f?x:0.f;
        r[j]=f2u(x);
      }
      o4 = *(const uint4*)r;
    }
    *(uint4*)&xt[row*72+seg*8]=o4;
  }
  float kr[49];
  size_t pxs=(size_t)t*3136 + (y0+ty)*56 + x0+tx;
  #pragma unroll
  for(int kk=0;kk<49;kk++) kr[kk]=b2f(kern[((size_t)b*49+kk)*PP+pxs]);
  __syncthreads();
  #pragma unroll
  for(int s=0;s<2;s++){
    int sub=2*w+s;
    float acc[8];
    #pragma unroll
    for(int e=0;e<8;e++) acc[e]=0;
    for(int i=0;i<7;i++){
      #pragma unroll
      for(int j=0;j<7;j++){
        uint4 u = *(const uint4*)&xt[((ty+i)*14+tx+j)*72 + sub*8];
        float kv = kr[i*7+j];
        acc[0]+=kv*blo(u.x); acc[1]+=kv*bhi(u.x);
        acc[2]+=kv*blo(u.y); acc[3]+=kv*bhi(u.y);
        acc[4]+=kv*blo(u.z); acc[5]+=kv*bhi(u.z);
        acc[6]+=kv*blo(u.w); acc[7]+=kv*bhi(u.w);
      }
    }
    unsigned pk[4];
    #pragma unroll
    for(int e=0;e<4;e++)
      pk[e] = (unsigned)f2u(acc[2*e]) | ((unsigned)f2u(acc[2*e+1])<<16);
    *(uint4*)&invT[((size_t)b*PP+pxs)*256 + c0 + sub*8] = make_uint4(pk[0],pk[1],pk[2],pk[3]);
  }
}

// ---- W2s = W_p2*diag(sc2) bf16; bias2 = b_p2 + W_p2@sh2 ----
__global__ void k_w2s(const float* wf, const float* sc2, const float* sh2,
                      us* W2sb, float* bias2){
  __shared__ float red[256];
  int o=blockIdx.x, ci=threadIdx.x;
  float wv = wf[oWP2 + ci*64 + o];
  W2sb[o*256+ci] = f2u(wv * sc2[ci]);
  red[ci] = wv * sh2[ci];
  __syncthreads();
  for(int st=128;st>0;st>>=1){ if(ci<st) red[ci]+=red[ci+st]; __syncthreads(); }
  if(ci==0) bias2[o] = wf[oBP2+o] + red[0];
}

// ---- out = W2s@invT + W_p2@xattT + bias2 ; both weight panels LDS-staged ----
__global__ __launch_bounds__(256) void k_final(const us* invT, const us* xattT,
                                               const us* W2sb, const us* Wp2b,
                                               const float* bias2, float* out){
  __shared__ us wt[32768];
  int tid=threadIdx.x; int w=tid>>6, l=tid&63;
  int pt=blockIdx.x, b=blockIdx.y;
  #pragma unroll
  for(int it=0;it<16;it++){
    int f = it*256+tid;
    int which = f>>11;
    int g = f&2047;
    int n=g>>9, kc=(g>>6)&7, lane=g&63;
    int co = n*16 + (lane&15);
    int ci = (lane>>4)*8 + kc*32;
    const us* src = which ? Wp2b : W2sb;
    uint4 v = *(const uint4*)(src + (size_t)co*256 + ci);
    *(uint4*)(wt + f*8) = v;
  }
  __syncthreads();
  int p0 = pt*64 + w*16;
  size_t abase = ((size_t)b*PP + p0 + (l&15))*256 + ((l>>4)*8);
  f32x4 acc[4];
  #pragma unroll
  for(int n=0;n<4;n++) acc[n]=(f32x4){0,0,0,0};
  for(int kc=0;kc<8;kc++){
    short8v ai = *(const short8v*)(invT + abase + kc*32);
    short8v ax = *(const short8v*)(xattT + abase + kc*32);
    #pragma unroll
    for(int n=0;n<4;n++){
      short8v b1 = *(const short8v*)(wt + ((n*8+kc)*64 + l)*8);
      acc[n] = __builtin_amdgcn_mfma_f32_16x16x32_bf16(ai,b1,acc[n],0,0,0);
      short8v b2 = *(const short8v*)(wt + 16384 + ((n*8+kc)*64 + l)*8);
      acc[n] = __builtin_amdgcn_mfma_f32_16x16x32_bf16(ax,b2,acc[n],0,0,0);
    }
  }
  int col=l&15, rowb=(l>>4)*4;
  #pragma unroll
  for(int n=0;n<4;n++){
    float bb = bias2[n*16+col];
    #pragma unroll
    for(int r=0;r<4;r++)
      out[((size_t)b*64 + n*16+col)*PP + p0 + rowb + r] = acc[n][r] + bb;
  }
}

extern "C" void kernel_launch(void* const* d_in, const int* in_sizes, int n_in,
                              void* d_out, int out_size, void* d_ws, size_t ws_size,
                              hipStream_t stream){
  const void* xct_r =d_in[0];
  const void* xwsi_r=d_in[1];
  const void* Wct =d_in[2];
  const void* bct =d_in[3];
  const void* Wwsi=d_in[4];
  const void* bwsi=d_in[5];
  const void* Watt=d_in[6];
  const void* Winv=d_in[7];
  const void* binv=d_in[8];
  const void* Wrr =d_in[9];
  const void* g1  =d_in[10];
  const void* be1 =d_in[11];
  const void* g2  =d_in[12];
  const void* be2 =d_in[13];
  const void* Wp1 =d_in[14];
  const void* Wp2 =d_in[16];
  const void* bp2 =d_in[17];
  float* ws=(float*)d_ws;
  float* xw1=ws+XW1o;
  float* Wx=ws+WXo; float* Wix=ws+WIXo;
  float* att=ws+ATTo;
  bf16* kern=(bf16*)(ws+KERNo);
  us* Wf=(us*)(ws+WXTo);
  us* Wrr2=(us*)(ws+WRR2o);
  bf16* xw3=(bf16*)(ws+XW3o);
  float* stat=ws+STATo; float* wf=ws+WFo;
  float* Wattf=ws+WATTFo; float* Winvf=ws+WINVFo;
  float* bias2=ws+WATTFo;     // aliases Wattf (dead after k_Wx)
  int* flag=(int*)(ws+FLAGo);
  bf16* bfb=(bf16*)(ws+BF16o);
  us* x1t=(us*)(bfb+bX1T);
  us* xattT=(us*)(bfb+bXATT); us* y1T=(us*)(bfb+bY1); us* invT=(us*)(bfb+bINV);
  us* Wp1b=(us*)(bfb+bWP1B); us* Wp2b=(us*)(bfb+bWP2B); us* W2sb=(us*)(bfb+bW2S);
  us* Wctb=(us*)(bfb+bWCTB);
  us* xwt=(us*)(bfb+bXWT);
  float* sum1=stat; float* sq1=stat+256; float* sum2=stat+512; float* sq2=stat+768;
  float* sc1=stat+1024; float* sh1=stat+1280; float* sc2=stat+1536; float* sh2=stat+1792;

  hipMemsetAsync(stat,0,4096,stream);
  hipMemsetAsync(Wix,0,6272*4,stream);
  k_detect<<<1,64,0,stream>>>((const us*)xct_r,flag);
  k_prep  <<<3733,256,0,stream>>>(Watt,Winv,Wct,bct,Wwsi,bwsi,Wrr,binv,Wp1,Wp2,bp2,
                                  Wattf,Winvf,wf,Wp1b,Wp2b,Wctb,flag);
  k_wsit  <<<dim3(49,12,2),256,0,stream>>>(xwsi_r,flag,xwt); // xwt aliases y1T head
  k_poolxw1<<<dim3(588,2),64,0,stream>>>(xwt,wf,xw1);
  k_Wx    <<<813,256,0,stream>>>(Wattf,xw1,Wx);
  k_Wfrag <<<1000,256,0,stream>>>(Wx,Wf);
  k_rrfrag<<<108,256,0,stream>>>(wf,Wrr2);                   // overwrites Wx head (dead)
  k_Winvx <<<dim3(25,8),256,0,stream>>>(Winvf,xw1,Wix);
  k_x1    <<<dim3(392,2),256,0,stream>>>(xct_r,flag,wf,Wctb,x1t); // MFMA GEMM
  k_att   <<<dim3(49,8,2),256,0,stream>>>(x1t,Wf,att);
  k_kern  <<<dim3(98,2),256,0,stream>>>(x1t,Wix,wf,kern);
  k_rr    <<<dim3(49,12,2),256,0,stream>>>(xwt,Wrr2,xw3);
  k_xatt  <<<dim3(392,2),256,0,stream>>>(xct_r,flag,xw3,att,xattT);
  k_p1    <<<dim3(392,4,2),256,0,stream>>>(xattT,Wp1b,y1T);  // overwrites xwt (dead)
  k_stats <<<dim3(392,2),256,0,stream>>>(y1T,sum1,sq1);
  k_finstat<<<1,256,0,stream>>>(sum1,sq1,g1,be1,flag,sc1,sh1);
  k_inv   <<<dim3(49,4,16),256,0,stream>>>(y1T,sc1,sh1,kern,invT);
  k_stats <<<dim3(392,2),256,0,stream>>>(invT,sum2,sq2);
  k_finstat<<<1,256,0,stream>>>(sum2,sq2,g2,be2,flag,sc2,sh2);
  k_w2s   <<<64,256,0,stream>>>(wf,sc2,sh2,W2sb,bias2);
  k_final <<<dim3(392,2),256,0,stream>>>(invT,xattT,W2sb,Wp2b,bias2,(float*)d_out);
}